// Round 13
// baseline (116.743 us; speedup 1.0000x reference)
//
#include <hip/hip_runtime.h>
#include <stdint.h>

// ---------- types ----------
typedef __attribute__((ext_vector_type(8)))  short          bf16x8;   // 8 bf16 (4 VGPRs)
typedef __attribute__((ext_vector_type(4)))  float          f32x4;
typedef __attribute__((ext_vector_type(16))) float          f32x16;
typedef __attribute__((ext_vector_type(4)))  unsigned int   u32x4;
typedef __attribute__((ext_vector_type(4)))  unsigned short u16x4;

// L=2048, N=2, E=1024, H=16, DH=64; SCALE=1/8; fold SCALE*log2(e) into Q so softmax uses exp2
#define SCALE_LOG2E 0.180336880f

static __device__ __forceinline__ unsigned short f2bf(float x) {
  union { float f; unsigned int u; } c; c.f = x;
  unsigned int r = c.u + 0x7fffu + ((c.u >> 16) & 1u);   // RNE
  return (unsigned short)(r >> 16);
}

// packed 2xf32 -> 2xbf16 in one VALU op (no builtin on gfx950 -> inline asm, per T12)
static __device__ __forceinline__ unsigned int cvt_pk_bf16(float lo, float hi) {
  unsigned int r;
  asm("v_cvt_pk_bf16_f32 %0, %1, %2" : "=v"(r) : "v"(lo), "v"(hi));
  return r;
}

static __device__ __forceinline__ void stage16(const unsigned short* g, unsigned short* l) {
  __builtin_amdgcn_global_load_lds(
      (const __attribute__((address_space(1))) unsigned int*)g,
      (__attribute__((address_space(3)))       unsigned int*)l, 16, 0, 0);
}

// ---------- f32 -> bf16 conversion ----------
__global__ __launch_bounds__(256) void cvt_f32_bf16(const float* __restrict__ src,
                                                    unsigned short* __restrict__ dst, int n) {
  int i = (blockIdx.x * 256 + threadIdx.x) * 4;
  if (i < n) {
    float4 v = *(const float4*)(src + i);
    u16x4 o; o.x = f2bf(v.x); o.y = f2bf(v.y); o.z = f2bf(v.z); o.w = f2bf(v.w);
    *(u16x4*)(dst + i) = o;
  }
}

// all 4 weight matrices in one launch; dst regions are consecutive (1M elems apart)
__global__ __launch_bounds__(256) void cvt_w4(const float* __restrict__ wq, const float* __restrict__ wk,
                                              const float* __restrict__ wv, const float* __restrict__ wo,
                                              unsigned short* __restrict__ dst) {
  const int z = blockIdx.y;
  const float* src = z == 0 ? wq : (z == 1 ? wk : (z == 2 ? wv : wo));
  int i = (blockIdx.x * 256 + threadIdx.x) * 4;
  float4 v = *(const float4*)(src + i);
  u16x4 o; o.x = f2bf(v.x); o.y = f2bf(v.y); o.z = f2bf(v.z); o.w = f2bf(v.w);
  *(u16x4*)(dst + (size_t)z * 1048576 + i) = o;
}

// ---------- GEMM core: C[128x128] tile of A[M][K] @ B[N][K]^T, bf16, K=1024 ----------
// R12: XOR-swizzled LDS k-chunks (T2); LDS dest linear, global source pre-swizzled (rule #21).
__device__ __forceinline__ void gemm_tile_core(const unsigned short* __restrict__ A,
                                               const unsigned short* __restrict__ B,
                                               int bi, int bj, f32x4 (&acc)[4][4]) {
  __shared__ unsigned short As[128 * 32];
  __shared__ unsigned short Bs[128 * 32];
  const int t = threadIdx.x, w = t >> 6, l = t & 63;
  const int l15 = l & 15, l4 = l >> 4;
  const int wm = w >> 1, wn = w & 1;
  const int srow = l >> 2;
  const int scol = ((l & 3) ^ ((l >> 3) & 3)) * 8;   // pre-swizzled source col (s = row bits 1-2)

#pragma unroll
  for (int m = 0; m < 4; m++)
#pragma unroll
    for (int n = 0; n < 4; n++)
#pragma unroll
      for (int r = 0; r < 4; r++) acc[m][n][r] = 0.f;

  const int koff = 8 * (l4 ^ ((l15 >> 1) & 3));      // swizzled read: slot l4^s holds kchunk l4
  for (int k0 = 0; k0 < 1024; k0 += 32) {
    stage16(A + (size_t)(bi * 128 + w * 16 + srow) * 1024 + k0 + scol, (unsigned short*)As + w * 512);
    stage16(A + (size_t)(bi * 128 + (w + 4) * 16 + srow) * 1024 + k0 + scol, (unsigned short*)As + (w + 4) * 512);
    stage16(B + (size_t)(bj * 128 + w * 16 + srow) * 1024 + k0 + scol, (unsigned short*)Bs + w * 512);
    stage16(B + (size_t)(bj * 128 + (w + 4) * 16 + srow) * 1024 + k0 + scol, (unsigned short*)Bs + (w + 4) * 512);
    __syncthreads();

    bf16x8 af[4], bfr[4];
#pragma unroll
    for (int m = 0; m < 4; m++) af[m]  = *(const bf16x8*)(As + (wm * 64 + m * 16 + l15) * 32 + koff);
#pragma unroll
    for (int n = 0; n < 4; n++) bfr[n] = *(const bf16x8*)(Bs + (wn * 64 + n * 16 + l15) * 32 + koff);
#pragma unroll
    for (int m = 0; m < 4; m++)
#pragma unroll
      for (int n = 0; n < 4; n++)
        acc[m][n] = __builtin_amdgcn_mfma_f32_16x16x32_bf16(af[m], bfr[n], acc[m][n], 0, 0, 0);
    __syncthreads();
  }
}

// ---------- QKV projection -> MFMA-fragment-order head layouts (R9-proven) ----------
// Qf/Kf: frag (b, kt=row/32, s=d>>4) -> 512 elems: lane = (row&31)+32*((d>>3)&1), e = d&7
// Vf:    frag (b, kt=kv/32, j=2*(d>>5)+((kv&31)>>4)) -> lane = (d&31)+32*(((kv&31)>>3)&1), e = kv&7
__global__ __launch_bounds__(256) void gemm_qkv(
    const unsigned short* __restrict__ X,
    const unsigned short* __restrict__ Wq, const unsigned short* __restrict__ Wk,
    const unsigned short* __restrict__ Wv,
    const float* __restrict__ bq, const float* __restrict__ bk, const float* __restrict__ bv,
    unsigned short* __restrict__ Qf, unsigned short* __restrict__ Kf, unsigned short* __restrict__ Vf) {
  const int mode = blockIdx.z;
  const unsigned short* W = mode == 0 ? Wq : (mode == 1 ? Wk : Wv);
  const float* bias = mode == 0 ? bq : (mode == 1 ? bk : bv);
  f32x4 acc[4][4];
  gemm_tile_core(X, W, blockIdx.y, blockIdx.x, acc);

  const int t = threadIdx.x, w = t >> 6, l = t & 63;
  const int l15 = l & 15, l4 = l >> 4;
  const int wm = w >> 1, wn = w & 1;
  const int i0 = blockIdx.y * 128 + wm * 64 + 4 * l4;
  const int j0 = blockIdx.x * 128 + wn * 64 + l15;
#pragma unroll
  for (int m = 0; m < 4; m++)
#pragma unroll
    for (int n = 0; n < 4; n++) {
      const int j = j0 + n * 16;
      const float bv_ = bias[j];
      const int h = j >> 6, d = j & 63;
#pragma unroll
      for (int r = 0; r < 4; r++) {
        const int i = i0 + m * 16 + r;
        const int n_ = i & 1, ll = i >> 1;     // row i of [L,N,E]: l = i/2, n = i%2
        const int b = n_ * 16 + h;
        const int kt = ll >> 5, l31k = ll & 31;
        float v = acc[m][n][r] + bv_;
        if (mode == 0) {
          const int lane = l31k + 32 * ((d >> 3) & 1);
          Qf[((size_t)(b * 64 + kt) * 4 + (d >> 4)) * 512 + lane * 8 + (d & 7)] = f2bf(v * SCALE_LOG2E);
        } else if (mode == 1) {
          const int lane = l31k + 32 * ((d >> 3) & 1);
          Kf[((size_t)(b * 64 + kt) * 4 + (d >> 4)) * 512 + lane * 8 + (d & 7)] = f2bf(v);
        } else {
          const int j2 = 2 * (d >> 5) + ((l31k >> 4) & 1);
          const int lane = (d & 31) + 32 * ((l31k >> 3) & 1);
          Vf[((size_t)(b * 64 + kt) * 4 + j2) * 512 + lane * 8 + (l31k & 7)] = f2bf(v);
        }
      }
    }
}

// ---------- output projection ----------
__global__ __launch_bounds__(256) void gemm_out(
    const unsigned short* __restrict__ X2, const unsigned short* __restrict__ Wo,
    const float* __restrict__ bias, float* __restrict__ out) {
  f32x4 acc[4][4];
  gemm_tile_core(X2, Wo, blockIdx.y, blockIdx.x, acc);
  const int t = threadIdx.x, w = t >> 6, l = t & 63;
  const int l15 = l & 15, l4 = l >> 4;
  const int wm = w >> 1, wn = w & 1;
  const int i0 = blockIdx.y * 128 + wm * 64 + 4 * l4;
  const int j0 = blockIdx.x * 128 + wn * 64 + l15;
#pragma unroll
  for (int m = 0; m < 4; m++)
#pragma unroll
    for (int n = 0; n < 4; n++) {
      const int j = j0 + n * 16;
      const float bv_ = bias[j];
#pragma unroll
      for (int r = 0; r < 4; r++)
        out[(size_t)(i0 + m * 16 + r) * 1024 + j] = acc[m][n][r] + bv_;
    }
}

// ---------- attention: softmax + PV step for one q-tile (R11-proven, unchanged) ----------
static __device__ __forceinline__ void tile_step(
    const f32x16& sa, bool diag, int l31, int g,
    float& lsum, f32x16& o0, f32x16& o1, const bf16x8 (&vf)[4]) {
  float e[16];
#pragma unroll
  for (int r = 0; r < 16; r++) e[r] = sa[r];
  if (diag) {
#pragma unroll
    for (int r = 0; r < 16; r++) {
      const int kvloc = (r & 3) + 8 * (r >> 2) + 4 * g;
      e[r] = (kvloc <= l31) ? e[r] : -30000.f;   // exp2(-30000) == 0
    }
  }
#pragma unroll
  for (int r = 0; r < 16; r++) e[r] = exp2f(e[r]);
  const float s0 = (e[0] + e[1]) + (e[2] + e[3]),   s1 = (e[4] + e[5]) + (e[6] + e[7]);
  const float s2 = (e[8] + e[9]) + (e[10] + e[11]), s3 = (e[12] + e[13]) + (e[14] + e[15]);
  lsum += (s0 + s1) + (s2 + s3);

  // P -> bf16 words; redistribute to PV B-operand layout via lane^32 (R7/R9-proven)
  unsigned int u[8], pu[8];
#pragma unroll
  for (int i = 0; i < 8; i++) u[i] = cvt_pk_bf16(e[2 * i], e[2 * i + 1]);
#pragma unroll
  for (int i = 0; i < 8; i++) pu[i] = (unsigned int)__shfl_xor((int)u[i], 32, 64);
  u32x4 B0, B1;
  B0.x = g ? pu[2] : u[0];  B0.y = g ? pu[3] : u[1];
  B0.z = g ? u[2] : pu[0];  B0.w = g ? u[3] : pu[1];
  B1.x = g ? pu[6] : u[4];  B1.y = g ? pu[7] : u[5];
  B1.z = g ? u[6] : pu[4];  B1.w = g ? u[7] : pu[5];
  const bf16x8 pb0 = __builtin_bit_cast(bf16x8, B0);  // kv 0..15
  const bf16x8 pb1 = __builtin_bit_cast(bf16x8, B1);  // kv 16..31
  o0 = __builtin_amdgcn_mfma_f32_32x32x16_bf16(vf[0], pb0, o0, 0, 0, 0);
  o0 = __builtin_amdgcn_mfma_f32_32x32x16_bf16(vf[1], pb1, o0, 0, 0, 0);
  o1 = __builtin_amdgcn_mfma_f32_32x32x16_bf16(vf[2], pb0, o1, 0, 0, 0);
  o1 = __builtin_amdgcn_mfma_f32_32x32x16_bf16(vf[3], pb1, o1, 0, 0, 0);
}

// ---------- causal flash attention, opposite-paired q-tiles ----------
// R13: per-wave PRIVATE LDS staging of K/V via global_load_lds (no dest regs -> compiler
// can't sink the prefetch; counted-vmcnt discipline per T3/T14). Single buffer per wave:
//   iter top: vmcnt(0) [tile ready] -> ds_read kf/vf -> lgkmcnt(0) [reads landed]
//   -> issue next tile's 8 gload_lds [fly under compute] -> compute.
// No in-loop barriers (buffers are wave-private). LDS 50 KB -> 3 blocks/CU.
__global__ __launch_bounds__(256, 3) void attn_kernel(
    const unsigned short* __restrict__ Qf, const unsigned short* __restrict__ Kf,
    const unsigned short* __restrict__ Vf, unsigned short* __restrict__ X2) {
  __shared__ unsigned short stg[4][4096];   // per-wave K(2048)+V(2048), 32 KB
  __shared__ float po[4 * 64 * 17];
  __shared__ float lb[2][4][32];

  const unsigned id = blockIdx.x;              // 1024 blocks
  const int b = (id & 7) * 4 + ((id >> 3) & 3);
  const int p = id >> 5;                       // 0..31: t1 = p, t2 = 63-p
  const int t2 = 63 - p;

  const int w = threadIdx.x >> 6, l = threadIdx.x & 63;
  const int l31 = l & 31, g = l >> 5;
  unsigned short* ws_ = stg[w];

  const unsigned short* qp1 = Qf + ((size_t)(b * 64 + p) * 4) * 512 + l * 8;
  const unsigned short* qp2 = Qf + ((size_t)(b * 64 + t2) * 4) * 512 + l * 8;
  bf16x8 qf1[4], qf2[4];
#pragma unroll
  for (int s = 0; s < 4; s++) { qf1[s] = *(const bf16x8*)(qp1 + s * 512); qf2[s] = *(const bf16x8*)(qp2 + s * 512); }

  const unsigned short* kb_ = Kf + (size_t)b * 131072;
  const unsigned short* vb_ = Vf + (size_t)b * 131072;

  // prologue: stage tile kt=w
  {
    const unsigned short* kp = kb_ + w * 2048;
    const unsigned short* vp = vb_ + w * 2048;
#pragma unroll
    for (int c = 0; c < 4; c++) {
      stage16(kp + c * 512 + l * 8, ws_ + c * 512);
      stage16(vp + c * 512 + l * 8, ws_ + 2048 + c * 512);
    }
  }

  f32x16 z;
#pragma unroll
  for (int r = 0; r < 16; r++) z[r] = 0.f;
  f32x16 o10 = z, o11 = z, o20 = z, o21 = z;
  float ls1 = 0.f, ls2 = 0.f;

  for (int kt = w; kt <= t2; kt += 4) {
    // current tile's staging complete (issued previous iter; flew under the compute)
    asm volatile("s_waitcnt vmcnt(0)" ::: "memory");
    __builtin_amdgcn_sched_barrier(0);
    bf16x8 kf[4], vf[4];
#pragma unroll
    for (int s = 0; s < 4; s++) {
      kf[s] = *(const bf16x8*)(ws_ + s * 512 + l * 8);
      vf[s] = *(const bf16x8*)(ws_ + 2048 + s * 512 + l * 8);
    }
    // reads must land in regs before the buffer is overwritten by the next staging
    asm volatile("s_waitcnt lgkmcnt(0)" ::: "memory");
    __builtin_amdgcn_sched_barrier(0);
    {
      const int ktn = (kt + 4 <= t2) ? kt + 4 : t2;   // clamp: redundant re-stage is harmless
      const unsigned short* kp = kb_ + ktn * 2048;
      const unsigned short* vp = vb_ + ktn * 2048;
#pragma unroll
      for (int c = 0; c < 4; c++) {
        stage16(kp + c * 512 + l * 8, ws_ + c * 512);
        stage16(vp + c * 512 + l * 8, ws_ + 2048 + c * 512);
      }
    }

    // tile2 (always active)
    f32x16 sa = __builtin_amdgcn_mfma_f32_32x32x16_bf16(kf[0], qf2[0], z, 0, 0, 0);
#pragma unroll
    for (int s = 1; s < 4; s++) sa = __builtin_amdgcn_mfma_f32_32x32x16_bf16(kf[s], qf2[s], sa, 0, 0, 0);
    tile_step(sa, kt == t2, l31, g, ls2, o20, o21, vf);

    // tile1 (active while kt <= p; wave-uniform branch)
    if (kt <= p) {
      f32x16 sb = __builtin_amdgcn_mfma_f32_32x32x16_bf16(kf[0], qf1[0], z, 0, 0, 0);
#pragma unroll
      for (int s = 1; s < 4; s++) sb = __builtin_amdgcn_mfma_f32_32x32x16_bf16(kf[s], qf1[s], sb, 0, 0, 0);
      tile_step(sb, kt == p, l31, g, ls1, o10, o11, vf);
    }
  }
  asm volatile("s_waitcnt vmcnt(0)" ::: "memory");   // drain last clamp staging

  // ---- cross-wave combine: 4 LDS passes (t1.o0, t1.o1, t2.o0, t2.o1); no max weights ----
  const float ls1f = ls1 + __shfl_xor(ls1, 32, 64);   // merge g=0/g=1 halves
  const float ls2f = ls2 + __shfl_xor(ls2, 32, 64);
  float* mypo = po + (w * 64 + l) * 17;
  if (l < 32) { lb[0][w][l] = ls1f; lb[1][w][l] = ls2f; }
#pragma unroll
  for (int r = 0; r < 16; r++) mypo[r] = o10[r];
  __syncthreads();

  const float inv1 = 1.f / (lb[0][0][l31] + lb[0][1][l31] + lb[0][2][l31] + lb[0][3][l31]);
  const float inv2 = 1.f / (lb[1][0][l31] + lb[1][1][l31] + lb[1][2][l31] + lb[1][3][l31]);

  const int n_ = b >> 4, h = b & 15;
  unsigned short* orow1 = X2 + ((size_t)((32 * p + l31) * 2 + n_)) * 1024 + h * 64;
  unsigned short* orow2 = X2 + ((size_t)((32 * t2 + l31) * 2 + n_)) * 1024 + h * 64;
  const int dbase = 8 * w + 4 * g;
  float c[4];

  // pass 1: t1 low half (already stored)
#pragma unroll
  for (int j = 0; j < 4; j++) c[j] = 0.f;
#pragma unroll
  for (int s = 0; s < 4; s++) {
    const float* pp = po + (s * 64 + l) * 17 + w * 4;
#pragma unroll
    for (int j = 0; j < 4; j++) c[j] += pp[j];
  }
#pragma unroll
  for (int j = 0; j < 4; j++) orow1[dbase + j] = f2bf(c[j] * inv1);
  __syncthreads();

  // pass 2: t1 high half
#pragma unroll
  for (int r = 0; r < 16; r++) mypo[r] = o11[r];
  __syncthreads();
#pragma unroll
  for (int j = 0; j < 4; j++) c[j] = 0.f;
#pragma unroll
  for (int s = 0; s < 4; s++) {
    const float* pp = po + (s * 64 + l) * 17 + w * 4;
#pragma unroll
    for (int j = 0; j < 4; j++) c[j] += pp[j];
  }
#pragma unroll
  for (int j = 0; j < 4; j++) orow1[32 + dbase + j] = f2bf(c[j] * inv1);
  __syncthreads();

  // pass 3: t2 low half
#pragma unroll
  for (int r = 0; r < 16; r++) mypo[r] = o20[r];
  __syncthreads();
#pragma unroll
  for (int j = 0; j < 4; j++) c[j] = 0.f;
#pragma unroll
  for (int s = 0; s < 4; s++) {
    const float* pp = po + (s * 64 + l) * 17 + w * 4;
#pragma unroll
    for (int j = 0; j < 4; j++) c[j] += pp[j];
  }
#pragma unroll
  for (int j = 0; j < 4; j++) orow2[dbase + j] = f2bf(c[j] * inv2);
  __syncthreads();

  // pass 4: t2 high half
#pragma unroll
  for (int r = 0; r < 16; r++) mypo[r] = o21[r];
  __syncthreads();
#pragma unroll
  for (int j = 0; j < 4; j++) c[j] = 0.f;
#pragma unroll
  for (int s = 0; s < 4; s++) {
    const float* pp = po + (s * 64 + l) * 17 + w * 4;
#pragma unroll
    for (int j = 0; j < 4; j++) c[j] += pp[j];
  }
#pragma unroll
  for (int j = 0; j < 4; j++) orow2[32 + dbase + j] = f2bf(c[j] * inv2);
}

// ---------- launch ----------
extern "C" void kernel_launch(void* const* d_in, const int* in_sizes, int n_in,
                              void* d_out, int out_size, void* d_ws, size_t ws_size,
                              hipStream_t stream) {
  const float* query    = (const float*)d_in[0];
  const float* q_proj   = (const float*)d_in[1];
  const float* q_bias   = (const float*)d_in[2];
  const float* k_proj   = (const float*)d_in[3];
  const float* k_bias   = (const float*)d_in[4];
  const float* v_proj   = (const float*)d_in[5];
  const float* v_bias   = (const float*)d_in[6];
  const float* out_proj = (const float*)d_in[7];
  const float* out_bias = (const float*)d_in[8];
  float* out = (float*)d_out;

  char* ws = (char*)d_ws;
  unsigned short* Xq = (unsigned short*)(ws);                    // [4096][1024] bf16, 8 MiB
  unsigned short* Wq = (unsigned short*)(ws + (8u << 20));       // 2 MiB each, consecutive
  unsigned short* Qf = (unsigned short*)(ws + (16u << 20));      // frag layout, 8 MiB
  unsigned short* Kf = (unsigned short*)(ws + (24u << 20));      // frag layout, 8 MiB
  unsigned short* Vf = (unsigned short*)(ws + (32u << 20));      // frag layout, 8 MiB
  unsigned short* X2 = (unsigned short*)(ws + (40u << 20));      // [4096][1024], 8 MiB
  unsigned short* Wk = Wq + 1048576;
  unsigned short* Wv = Wq + 2097152;
  unsigned short* Wo = Wq + 3145728;

  cvt_f32_bf16<<<4096, 256, 0, stream>>>(query, Xq, 4194304);
  cvt_w4<<<dim3(1024, 4), 256, 0, stream>>>(q_proj, k_proj, v_proj, out_proj, Wq);

  gemm_qkv<<<dim3(8, 32, 3), 256, 0, stream>>>(Xq, Wq, Wk, Wv, q_bias, k_bias, v_bias, Qf, Kf, Vf);
  attn_kernel<<<1024, 256, 0, stream>>>(Qf, Kf, Vf, X2);
  gemm_out<<<dim3(8, 32), 256, 0, stream>>>(X2, Wo, out_bias, out);
}

// Round 14
// 113.470 us; speedup vs baseline: 1.0288x; 1.0288x over previous
//
#include <hip/hip_runtime.h>
#include <stdint.h>

// ---------- types ----------
typedef __attribute__((ext_vector_type(8)))  short          bf16x8;   // 8 bf16 (4 VGPRs)
typedef __attribute__((ext_vector_type(4)))  float          f32x4;
typedef __attribute__((ext_vector_type(16))) float          f32x16;
typedef __attribute__((ext_vector_type(4)))  unsigned int   u32x4;
typedef __attribute__((ext_vector_type(4)))  unsigned short u16x4;

// L=2048, N=2, E=1024, H=16, DH=64; SCALE=1/8; fold SCALE*log2(e) into Q so softmax uses exp2
#define SCALE_LOG2E 0.180336880f

static __device__ __forceinline__ unsigned short f2bf(float x) {
  union { float f; unsigned int u; } c; c.f = x;
  unsigned int r = c.u + 0x7fffu + ((c.u >> 16) & 1u);   // RNE
  return (unsigned short)(r >> 16);
}

// packed 2xf32 -> 2xbf16 in one VALU op (no builtin on gfx950 -> inline asm, per T12)
static __device__ __forceinline__ unsigned int cvt_pk_bf16(float lo, float hi) {
  unsigned int r;
  asm("v_cvt_pk_bf16_f32 %0, %1, %2" : "=v"(r) : "v"(lo), "v"(hi));
  return r;
}

// pinned 16B global load: asm volatile CANNOT be sunk/renamed by the scheduler
// (R6/R7/R13 all failed to keep a C++ prefetch live; this is the mechanical fix)
static __device__ __forceinline__ void gld16(u32x4& dst, const unsigned short* a) {
  asm volatile("global_load_dwordx4 %0, %1, off" : "=v"(dst) : "v"(a));
}

static __device__ __forceinline__ void stage16(const unsigned short* g, unsigned short* l) {
  __builtin_amdgcn_global_load_lds(
      (const __attribute__((address_space(1))) unsigned int*)g,
      (__attribute__((address_space(3)))       unsigned int*)l, 16, 0, 0);
}

// ---------- f32 -> bf16 conversion ----------
__global__ __launch_bounds__(256) void cvt_f32_bf16(const float* __restrict__ src,
                                                    unsigned short* __restrict__ dst, int n) {
  int i = (blockIdx.x * 256 + threadIdx.x) * 4;
  if (i < n) {
    float4 v = *(const float4*)(src + i);
    u16x4 o; o.x = f2bf(v.x); o.y = f2bf(v.y); o.z = f2bf(v.z); o.w = f2bf(v.w);
    *(u16x4*)(dst + i) = o;
  }
}

// all 4 weight matrices in one launch; dst regions are consecutive (1M elems apart)
__global__ __launch_bounds__(256) void cvt_w4(const float* __restrict__ wq, const float* __restrict__ wk,
                                              const float* __restrict__ wv, const float* __restrict__ wo,
                                              unsigned short* __restrict__ dst) {
  const int z = blockIdx.y;
  const float* src = z == 0 ? wq : (z == 1 ? wk : (z == 2 ? wv : wo));
  int i = (blockIdx.x * 256 + threadIdx.x) * 4;
  float4 v = *(const float4*)(src + i);
  u16x4 o; o.x = f2bf(v.x); o.y = f2bf(v.y); o.z = f2bf(v.z); o.w = f2bf(v.w);
  *(u16x4*)(dst + (size_t)z * 1048576 + i) = o;
}

// ---------- GEMM core: C[128x128] tile of A[M][K] @ B[N][K]^T, bf16, K=1024 ----------
// R12: XOR-swizzled LDS k-chunks (T2); LDS dest linear, global source pre-swizzled (rule #21).
__device__ __forceinline__ void gemm_tile_core(const unsigned short* __restrict__ A,
                                               const unsigned short* __restrict__ B,
                                               int bi, int bj, f32x4 (&acc)[4][4]) {
  __shared__ unsigned short As[128 * 32];
  __shared__ unsigned short Bs[128 * 32];
  const int t = threadIdx.x, w = t >> 6, l = t & 63;
  const int l15 = l & 15, l4 = l >> 4;
  const int wm = w >> 1, wn = w & 1;
  const int srow = l >> 2;
  const int scol = ((l & 3) ^ ((l >> 3) & 3)) * 8;   // pre-swizzled source col (s = row bits 1-2)

#pragma unroll
  for (int m = 0; m < 4; m++)
#pragma unroll
    for (int n = 0; n < 4; n++)
#pragma unroll
      for (int r = 0; r < 4; r++) acc[m][n][r] = 0.f;

  const int koff = 8 * (l4 ^ ((l15 >> 1) & 3));      // swizzled read: slot l4^s holds kchunk l4
  for (int k0 = 0; k0 < 1024; k0 += 32) {
    stage16(A + (size_t)(bi * 128 + w * 16 + srow) * 1024 + k0 + scol, (unsigned short*)As + w * 512);
    stage16(A + (size_t)(bi * 128 + (w + 4) * 16 + srow) * 1024 + k0 + scol, (unsigned short*)As + (w + 4) * 512);
    stage16(B + (size_t)(bj * 128 + w * 16 + srow) * 1024 + k0 + scol, (unsigned short*)Bs + w * 512);
    stage16(B + (size_t)(bj * 128 + (w + 4) * 16 + srow) * 1024 + k0 + scol, (unsigned short*)Bs + (w + 4) * 512);
    __syncthreads();

    bf16x8 af[4], bfr[4];
#pragma unroll
    for (int m = 0; m < 4; m++) af[m]  = *(const bf16x8*)(As + (wm * 64 + m * 16 + l15) * 32 + koff);
#pragma unroll
    for (int n = 0; n < 4; n++) bfr[n] = *(const bf16x8*)(Bs + (wn * 64 + n * 16 + l15) * 32 + koff);
#pragma unroll
    for (int m = 0; m < 4; m++)
#pragma unroll
      for (int n = 0; n < 4; n++)
        acc[m][n] = __builtin_amdgcn_mfma_f32_16x16x32_bf16(af[m], bfr[n], acc[m][n], 0, 0, 0);
    __syncthreads();
  }
}

// ---------- QKV projection -> MFMA-fragment-order head layouts (R9-proven) ----------
// Qf/Kf: frag (b, kt=row/32, s=d>>4) -> 512 elems: lane = (row&31)+32*((d>>3)&1), e = d&7
// Vf:    frag (b, kt=kv/32, j=2*(d>>5)+((kv&31)>>4)) -> lane = (d&31)+32*(((kv&31)>>3)&1), e = kv&7
__global__ __launch_bounds__(256) void gemm_qkv(
    const unsigned short* __restrict__ X,
    const unsigned short* __restrict__ Wq, const unsigned short* __restrict__ Wk,
    const unsigned short* __restrict__ Wv,
    const float* __restrict__ bq, const float* __restrict__ bk, const float* __restrict__ bv,
    unsigned short* __restrict__ Qf, unsigned short* __restrict__ Kf, unsigned short* __restrict__ Vf) {
  const int mode = blockIdx.z;
  const unsigned short* W = mode == 0 ? Wq : (mode == 1 ? Wk : Wv);
  const float* bias = mode == 0 ? bq : (mode == 1 ? bk : bv);
  f32x4 acc[4][4];
  gemm_tile_core(X, W, blockIdx.y, blockIdx.x, acc);

  const int t = threadIdx.x, w = t >> 6, l = t & 63;
  const int l15 = l & 15, l4 = l >> 4;
  const int wm = w >> 1, wn = w & 1;
  const int i0 = blockIdx.y * 128 + wm * 64 + 4 * l4;
  const int j0 = blockIdx.x * 128 + wn * 64 + l15;
#pragma unroll
  for (int m = 0; m < 4; m++)
#pragma unroll
    for (int n = 0; n < 4; n++) {
      const int j = j0 + n * 16;
      const float bv_ = bias[j];
      const int h = j >> 6, d = j & 63;
#pragma unroll
      for (int r = 0; r < 4; r++) {
        const int i = i0 + m * 16 + r;
        const int n_ = i & 1, ll = i >> 1;     // row i of [L,N,E]: l = i/2, n = i%2
        const int b = n_ * 16 + h;
        const int kt = ll >> 5, l31k = ll & 31;
        float v = acc[m][n][r] + bv_;
        if (mode == 0) {
          const int lane = l31k + 32 * ((d >> 3) & 1);
          Qf[((size_t)(b * 64 + kt) * 4 + (d >> 4)) * 512 + lane * 8 + (d & 7)] = f2bf(v * SCALE_LOG2E);
        } else if (mode == 1) {
          const int lane = l31k + 32 * ((d >> 3) & 1);
          Kf[((size_t)(b * 64 + kt) * 4 + (d >> 4)) * 512 + lane * 8 + (d & 7)] = f2bf(v);
        } else {
          const int j2 = 2 * (d >> 5) + ((l31k >> 4) & 1);
          const int lane = (d & 31) + 32 * ((l31k >> 3) & 1);
          Vf[((size_t)(b * 64 + kt) * 4 + j2) * 512 + lane * 8 + (l31k & 7)] = f2bf(v);
        }
      }
    }
}

// ---------- output projection ----------
__global__ __launch_bounds__(256) void gemm_out(
    const unsigned short* __restrict__ X2, const unsigned short* __restrict__ Wo,
    const float* __restrict__ bias, float* __restrict__ out) {
  f32x4 acc[4][4];
  gemm_tile_core(X2, Wo, blockIdx.y, blockIdx.x, acc);
  const int t = threadIdx.x, w = t >> 6, l = t & 63;
  const int l15 = l & 15, l4 = l >> 4;
  const int wm = w >> 1, wn = w & 1;
  const int i0 = blockIdx.y * 128 + wm * 64 + 4 * l4;
  const int j0 = blockIdx.x * 128 + wn * 64 + l15;
#pragma unroll
  for (int m = 0; m < 4; m++)
#pragma unroll
    for (int n = 0; n < 4; n++) {
      const int j = j0 + n * 16;
      const float bv_ = bias[j];
#pragma unroll
      for (int r = 0; r < 4; r++)
        out[(size_t)(i0 + m * 16 + r) * 1024 + j] = acc[m][n][r] + bv_;
    }
}

// ---------- attention: softmax + PV step for one q-tile (R11-proven, unchanged) ----------
static __device__ __forceinline__ void tile_step(
    const f32x16& sa, bool diag, int l31, int g,
    float& lsum, f32x16& o0, f32x16& o1, const bf16x8 (&vf)[4]) {
  float e[16];
#pragma unroll
  for (int r = 0; r < 16; r++) e[r] = sa[r];
  if (diag) {
#pragma unroll
    for (int r = 0; r < 16; r++) {
      const int kvloc = (r & 3) + 8 * (r >> 2) + 4 * g;
      e[r] = (kvloc <= l31) ? e[r] : -30000.f;   // exp2(-30000) == 0
    }
  }
#pragma unroll
  for (int r = 0; r < 16; r++) e[r] = exp2f(e[r]);
  const float s0 = (e[0] + e[1]) + (e[2] + e[3]),   s1 = (e[4] + e[5]) + (e[6] + e[7]);
  const float s2 = (e[8] + e[9]) + (e[10] + e[11]), s3 = (e[12] + e[13]) + (e[14] + e[15]);
  lsum += (s0 + s1) + (s2 + s3);

  // P -> bf16 words; redistribute to PV B-operand layout via lane^32 (R7/R9-proven)
  unsigned int u[8], pu[8];
#pragma unroll
  for (int i = 0; i < 8; i++) u[i] = cvt_pk_bf16(e[2 * i], e[2 * i + 1]);
#pragma unroll
  for (int i = 0; i < 8; i++) pu[i] = (unsigned int)__shfl_xor((int)u[i], 32, 64);
  u32x4 B0, B1;
  B0.x = g ? pu[2] : u[0];  B0.y = g ? pu[3] : u[1];
  B0.z = g ? u[2] : pu[0];  B0.w = g ? u[3] : pu[1];
  B1.x = g ? pu[6] : u[4];  B1.y = g ? pu[7] : u[5];
  B1.z = g ? u[6] : pu[4];  B1.w = g ? u[7] : pu[5];
  const bf16x8 pb0 = __builtin_bit_cast(bf16x8, B0);  // kv 0..15
  const bf16x8 pb1 = __builtin_bit_cast(bf16x8, B1);  // kv 16..31
  o0 = __builtin_amdgcn_mfma_f32_32x32x16_bf16(vf[0], pb0, o0, 0, 0, 0);
  o0 = __builtin_amdgcn_mfma_f32_32x32x16_bf16(vf[1], pb1, o0, 0, 0, 0);
  o1 = __builtin_amdgcn_mfma_f32_32x32x16_bf16(vf[2], pb0, o1, 0, 0, 0);
  o1 = __builtin_amdgcn_mfma_f32_32x32x16_bf16(vf[3], pb1, o1, 0, 0, 0);
}

// ---------- causal flash attention, opposite-paired q-tiles ----------
// R14: R12 structure (LDS/epilogue/launch_bounds identical); K/V prefetch now via
// asm-volatile global_load_dwordx4 (gld16) -> the compiler CANNOT sink/rename it.
// Per iter: issue next tile's 8 loads (pinned) -> compute current -> vmcnt(0)+sched_barrier
// (rule #18) -> rotate regs. Loads fly under ~600-800 cyc of compute.
__global__ __launch_bounds__(256, 2) void attn_kernel(
    const unsigned short* __restrict__ Qf, const unsigned short* __restrict__ Kf,
    const unsigned short* __restrict__ Vf, unsigned short* __restrict__ X2) {
  __shared__ float po[4 * 64 * 17];
  __shared__ float lb[2][4][32];

  const unsigned id = blockIdx.x;              // 1024 blocks
  const int b = (id & 7) * 4 + ((id >> 3) & 3);
  const int p = id >> 5;                       // 0..31: t1 = p, t2 = 63-p
  const int t2 = 63 - p;

  const int w = threadIdx.x >> 6, l = threadIdx.x & 63;
  const int l31 = l & 31, g = l >> 5;

  const unsigned short* qp1 = Qf + ((size_t)(b * 64 + p) * 4) * 512 + l * 8;
  const unsigned short* qp2 = Qf + ((size_t)(b * 64 + t2) * 4) * 512 + l * 8;
  bf16x8 qf1[4], qf2[4];
#pragma unroll
  for (int s = 0; s < 4; s++) { qf1[s] = *(const bf16x8*)(qp1 + s * 512); qf2[s] = *(const bf16x8*)(qp2 + s * 512); }

  f32x16 z;
#pragma unroll
  for (int r = 0; r < 16; r++) z[r] = 0.f;
  f32x16 o10 = z, o11 = z, o20 = z, o21 = z;
  float ls1 = 0.f, ls2 = 0.f;

  const unsigned short* kb_ = Kf + (size_t)b * 131072;
  const unsigned short* vb_ = Vf + (size_t)b * 131072;

  u32x4 kc[4], vc[4], kn[4], vn[4];
  // prologue: pinned loads of tile kt=w, then drain
  {
    const unsigned short* kp = kb_ + w * 2048 + l * 8;
    const unsigned short* vp = vb_ + w * 2048 + l * 8;
#pragma unroll
    for (int s = 0; s < 4; s++) { gld16(kc[s], kp + s * 512); gld16(vc[s], vp + s * 512); }
    asm volatile("s_waitcnt vmcnt(0)" ::: "memory");
    __builtin_amdgcn_sched_barrier(0);
  }

  for (int kt = w; kt <= t2; kt += 4) {
    // issue next tile's loads (clamped; duplicate last load is an L2 hit) — pinned here
    const int ktn = (kt + 4 <= t2) ? kt + 4 : t2;
    const unsigned short* kp = kb_ + ktn * 2048 + l * 8;
    const unsigned short* vp = vb_ + ktn * 2048 + l * 8;
#pragma unroll
    for (int s = 0; s < 4; s++) { gld16(kn[s], kp + s * 512); gld16(vn[s], vp + s * 512); }

    bf16x8 kf[4], vf[4];
#pragma unroll
    for (int s = 0; s < 4; s++) { kf[s] = __builtin_bit_cast(bf16x8, kc[s]); vf[s] = __builtin_bit_cast(bf16x8, vc[s]); }

    // tile2 (always active)
    f32x16 sa = __builtin_amdgcn_mfma_f32_32x32x16_bf16(kf[0], qf2[0], z, 0, 0, 0);
#pragma unroll
    for (int s = 1; s < 4; s++) sa = __builtin_amdgcn_mfma_f32_32x32x16_bf16(kf[s], qf2[s], sa, 0, 0, 0);
    tile_step(sa, kt == t2, l31, g, ls2, o20, o21, vf);

    // tile1 (active while kt <= p; wave-uniform branch)
    if (kt <= p) {
      f32x16 sb = __builtin_amdgcn_mfma_f32_32x32x16_bf16(kf[0], qf1[0], z, 0, 0, 0);
#pragma unroll
      for (int s = 1; s < 4; s++) sb = __builtin_amdgcn_mfma_f32_32x32x16_bf16(kf[s], qf1[s], sb, 0, 0, 0);
      tile_step(sb, kt == p, l31, g, ls1, o10, o11, vf);
    }

    // next tile's loads must have landed; block any motion across (rule #18)
    asm volatile("s_waitcnt vmcnt(0)" ::: "memory");
    __builtin_amdgcn_sched_barrier(0);
#pragma unroll
    for (int s = 0; s < 4; s++) { kc[s] = kn[s]; vc[s] = vn[s]; }
  }

  // ---- cross-wave combine: 4 LDS passes (t1.o0, t1.o1, t2.o0, t2.o1); no max weights ----
  const float ls1f = ls1 + __shfl_xor(ls1, 32, 64);   // merge g=0/g=1 halves
  const float ls2f = ls2 + __shfl_xor(ls2, 32, 64);
  float* mypo = po + (w * 64 + l) * 17;
  if (l < 32) { lb[0][w][l] = ls1f; lb[1][w][l] = ls2f; }
#pragma unroll
  for (int r = 0; r < 16; r++) mypo[r] = o10[r];
  __syncthreads();

  const float inv1 = 1.f / (lb[0][0][l31] + lb[0][1][l31] + lb[0][2][l31] + lb[0][3][l31]);
  const float inv2 = 1.f / (lb[1][0][l31] + lb[1][1][l31] + lb[1][2][l31] + lb[1][3][l31]);

  const int n_ = b >> 4, h = b & 15;
  unsigned short* orow1 = X2 + ((size_t)((32 * p + l31) * 2 + n_)) * 1024 + h * 64;
  unsigned short* orow2 = X2 + ((size_t)((32 * t2 + l31) * 2 + n_)) * 1024 + h * 64;
  const int dbase = 8 * w + 4 * g;
  float c[4];

  // pass 1: t1 low half (already stored)
#pragma unroll
  for (int j = 0; j < 4; j++) c[j] = 0.f;
#pragma unroll
  for (int s = 0; s < 4; s++) {
    const float* pp = po + (s * 64 + l) * 17 + w * 4;
#pragma unroll
    for (int j = 0; j < 4; j++) c[j] += pp[j];
  }
#pragma unroll
  for (int j = 0; j < 4; j++) orow1[dbase + j] = f2bf(c[j] * inv1);
  __syncthreads();

  // pass 2: t1 high half
#pragma unroll
  for (int r = 0; r < 16; r++) mypo[r] = o11[r];
  __syncthreads();
#pragma unroll
  for (int j = 0; j < 4; j++) c[j] = 0.f;
#pragma unroll
  for (int s = 0; s < 4; s++) {
    const float* pp = po + (s * 64 + l) * 17 + w * 4;
#pragma unroll
    for (int j = 0; j < 4; j++) c[j] += pp[j];
  }
#pragma unroll
  for (int j = 0; j < 4; j++) orow1[32 + dbase + j] = f2bf(c[j] * inv1);
  __syncthreads();

  // pass 3: t2 low half
#pragma unroll
  for (int r = 0; r < 16; r++) mypo[r] = o20[r];
  __syncthreads();
#pragma unroll
  for (int j = 0; j < 4; j++) c[j] = 0.f;
#pragma unroll
  for (int s = 0; s < 4; s++) {
    const float* pp = po + (s * 64 + l) * 17 + w * 4;
#pragma unroll
    for (int j = 0; j < 4; j++) c[j] += pp[j];
  }
#pragma unroll
  for (int j = 0; j < 4; j++) orow2[dbase + j] = f2bf(c[j] * inv2);
  __syncthreads();

  // pass 4: t2 high half
#pragma unroll
  for (int r = 0; r < 16; r++) mypo[r] = o21[r];
  __syncthreads();
#pragma unroll
  for (int j = 0; j < 4; j++) c[j] = 0.f;
#pragma unroll
  for (int s = 0; s < 4; s++) {
    const float* pp = po + (s * 64 + l) * 17 + w * 4;
#pragma unroll
    for (int j = 0; j < 4; j++) c[j] += pp[j];
  }
#pragma unroll
  for (int j = 0; j < 4; j++) orow2[32 + dbase + j] = f2bf(c[j] * inv2);
}

// ---------- launch ----------
extern "C" void kernel_launch(void* const* d_in, const int* in_sizes, int n_in,
                              void* d_out, int out_size, void* d_ws, size_t ws_size,
                              hipStream_t stream) {
  const float* query    = (const float*)d_in[0];
  const float* q_proj   = (const float*)d_in[1];
  const float* q_bias   = (const float*)d_in[2];
  const float* k_proj   = (const float*)d_in[3];
  const float* k_bias   = (const float*)d_in[4];
  const float* v_proj   = (const float*)d_in[5];
  const float* v_bias   = (const float*)d_in[6];
  const float* out_proj = (const float*)d_in[7];
  const float* out_bias = (const float*)d_in[8];
  float* out = (float*)d_out;

  char* ws = (char*)d_ws;
  unsigned short* Xq = (unsigned short*)(ws);                    // [4096][1024] bf16, 8 MiB
  unsigned short* Wq = (unsigned short*)(ws + (8u << 20));       // 2 MiB each, consecutive
  unsigned short* Qf = (unsigned short*)(ws + (16u << 20));      // frag layout, 8 MiB
  unsigned short* Kf = (unsigned short*)(ws + (24u << 20));      // frag layout, 8 MiB
  unsigned short* Vf = (unsigned short*)(ws + (32u << 20));      // frag layout, 8 MiB
  unsigned short* X2 = (unsigned short*)(ws + (40u << 20));      // [4096][1024], 8 MiB
  unsigned short* Wk = Wq + 1048576;
  unsigned short* Wv = Wq + 2097152;
  unsigned short* Wo = Wq + 3145728;

  cvt_f32_bf16<<<4096, 256, 0, stream>>>(query, Xq, 4194304);
  cvt_w4<<<dim3(1024, 4), 256, 0, stream>>>(q_proj, k_proj, v_proj, out_proj, Wq);

  gemm_qkv<<<dim3(8, 32, 3), 256, 0, stream>>>(Xq, Wq, Wk, Wv, q_bias, k_bias, v_bias, Qf, Kf, Vf);
  attn_kernel<<<1024, 256, 0, stream>>>(Qf, Kf, Vf, X2);
  gemm_out<<<dim3(8, 32), 256, 0, stream>>>(X2, Wo, out_bias, out);
}

// Round 15
// 106.832 us; speedup vs baseline: 1.0928x; 1.0621x over previous
//
#include <hip/hip_runtime.h>
#include <stdint.h>

// ---------- types ----------
typedef __attribute__((ext_vector_type(8)))  short          bf16x8;   // 8 bf16 (4 VGPRs)
typedef __attribute__((ext_vector_type(4)))  float          f32x4;
typedef __attribute__((ext_vector_type(16))) float          f32x16;
typedef __attribute__((ext_vector_type(4)))  unsigned int   u32x4;
typedef __attribute__((ext_vector_type(4)))  unsigned short u16x4;

// L=2048, N=2, E=1024, H=16, DH=64; SCALE=1/8; fold SCALE*log2(e) into Q so softmax uses exp2
#define SCALE_LOG2E 0.180336880f

static __device__ __forceinline__ unsigned short f2bf(float x) {
  union { float f; unsigned int u; } c; c.f = x;
  unsigned int r = c.u + 0x7fffu + ((c.u >> 16) & 1u);   // RNE
  return (unsigned short)(r >> 16);
}

// packed 2xf32 -> 2xbf16 in one VALU op (no builtin on gfx950 -> inline asm, per T12)
static __device__ __forceinline__ unsigned int cvt_pk_bf16(float lo, float hi) {
  unsigned int r;
  asm("v_cvt_pk_bf16_f32 %0, %1, %2" : "=v"(r) : "v"(lo), "v"(hi));
  return r;
}

static __device__ __forceinline__ void stage16(const unsigned short* g, unsigned short* l) {
  __builtin_amdgcn_global_load_lds(
      (const __attribute__((address_space(1))) unsigned int*)g,
      (__attribute__((address_space(3)))       unsigned int*)l, 16, 0, 0);
}

// ---------- merged f32 -> bf16 conversion (query + 4 weights, one launch) ----------
// blocks 0..4095: query (4.19M elems -> Xq); blocks 4096..8191: weights z=(blk-4096)>>10
__global__ __launch_bounds__(256) void cvt_all(const float* __restrict__ query,
                                               const float* __restrict__ wq, const float* __restrict__ wk,
                                               const float* __restrict__ wv, const float* __restrict__ wo,
                                               unsigned short* __restrict__ Xq,
                                               unsigned short* __restrict__ Wdst) {
  const int blk = blockIdx.x;
  const float* src;
  unsigned short* dst;
  int i;
  if (blk < 4096) {
    src = query; dst = Xq;
    i = (blk * 256 + threadIdx.x) * 4;
  } else {
    const int z = (blk - 4096) >> 10;
    const int x = (blk - 4096) & 1023;
    src = z == 0 ? wq : (z == 1 ? wk : (z == 2 ? wv : wo));
    dst = Wdst + (size_t)z * 1048576;
    i = (x * 256 + threadIdx.x) * 4;
  }
  float4 v = *(const float4*)(src + i);
  u16x4 o; o.x = f2bf(v.x); o.y = f2bf(v.y); o.z = f2bf(v.z); o.w = f2bf(v.w);
  *(u16x4*)(dst + i) = o;
}

// ---------- GEMM core: C[128x128] tile of A[M][K] @ B[N][K]^T, bf16, K=1024 ----------
// R12: XOR-swizzled LDS k-chunks (T2); LDS dest linear, global source pre-swizzled (rule #21).
__device__ __forceinline__ void gemm_tile_core(const unsigned short* __restrict__ A,
                                               const unsigned short* __restrict__ B,
                                               int bi, int bj, f32x4 (&acc)[4][4]) {
  __shared__ unsigned short As[128 * 32];
  __shared__ unsigned short Bs[128 * 32];
  const int t = threadIdx.x, w = t >> 6, l = t & 63;
  const int l15 = l & 15, l4 = l >> 4;
  const int wm = w >> 1, wn = w & 1;
  const int srow = l >> 2;
  const int scol = ((l & 3) ^ ((l >> 3) & 3)) * 8;   // pre-swizzled source col (s = row bits 1-2)

#pragma unroll
  for (int m = 0; m < 4; m++)
#pragma unroll
    for (int n = 0; n < 4; n++)
#pragma unroll
      for (int r = 0; r < 4; r++) acc[m][n][r] = 0.f;

  const int koff = 8 * (l4 ^ ((l15 >> 1) & 3));      // swizzled read: slot l4^s holds kchunk l4
  for (int k0 = 0; k0 < 1024; k0 += 32) {
    stage16(A + (size_t)(bi * 128 + w * 16 + srow) * 1024 + k0 + scol, (unsigned short*)As + w * 512);
    stage16(A + (size_t)(bi * 128 + (w + 4) * 16 + srow) * 1024 + k0 + scol, (unsigned short*)As + (w + 4) * 512);
    stage16(B + (size_t)(bj * 128 + w * 16 + srow) * 1024 + k0 + scol, (unsigned short*)Bs + w * 512);
    stage16(B + (size_t)(bj * 128 + (w + 4) * 16 + srow) * 1024 + k0 + scol, (unsigned short*)Bs + (w + 4) * 512);
    __syncthreads();

    bf16x8 af[4], bfr[4];
#pragma unroll
    for (int m = 0; m < 4; m++) af[m]  = *(const bf16x8*)(As + (wm * 64 + m * 16 + l15) * 32 + koff);
#pragma unroll
    for (int n = 0; n < 4; n++) bfr[n] = *(const bf16x8*)(Bs + (wn * 64 + n * 16 + l15) * 32 + koff);
#pragma unroll
    for (int m = 0; m < 4; m++)
#pragma unroll
      for (int n = 0; n < 4; n++)
        acc[m][n] = __builtin_amdgcn_mfma_f32_16x16x32_bf16(af[m], bfr[n], acc[m][n], 0, 0, 0);
    __syncthreads();
  }
}

// ---------- QKV projection -> MFMA-fragment-order head layouts (R9-proven) ----------
// Qf/Kf: frag (b, kt=row/32, s=d>>4) -> 512 elems: lane = (row&31)+32*((d>>3)&1), e = d&7
// Vf:    frag (b, kt=kv/32, j=2*(d>>5)+((kv&31)>>4)) -> lane = (d&31)+32*(((kv&31)>>3)&1), e = kv&7
__global__ __launch_bounds__(256) void gemm_qkv(
    const unsigned short* __restrict__ X,
    const unsigned short* __restrict__ Wq, const unsigned short* __restrict__ Wk,
    const unsigned short* __restrict__ Wv,
    const float* __restrict__ bq, const float* __restrict__ bk, const float* __restrict__ bv,
    unsigned short* __restrict__ Qf, unsigned short* __restrict__ Kf, unsigned short* __restrict__ Vf) {
  const int mode = blockIdx.z;
  const unsigned short* W = mode == 0 ? Wq : (mode == 1 ? Wk : Wv);
  const float* bias = mode == 0 ? bq : (mode == 1 ? bk : bv);
  f32x4 acc[4][4];
  gemm_tile_core(X, W, blockIdx.y, blockIdx.x, acc);

  const int t = threadIdx.x, w = t >> 6, l = t & 63;
  const int l15 = l & 15, l4 = l >> 4;
  const int wm = w >> 1, wn = w & 1;
  const int i0 = blockIdx.y * 128 + wm * 64 + 4 * l4;
  const int j0 = blockIdx.x * 128 + wn * 64 + l15;
#pragma unroll
  for (int m = 0; m < 4; m++)
#pragma unroll
    for (int n = 0; n < 4; n++) {
      const int j = j0 + n * 16;
      const float bv_ = bias[j];
      const int h = j >> 6, d = j & 63;
#pragma unroll
      for (int r = 0; r < 4; r++) {
        const int i = i0 + m * 16 + r;
        const int n_ = i & 1, ll = i >> 1;     // row i of [L,N,E]: l = i/2, n = i%2
        const int b = n_ * 16 + h;
        const int kt = ll >> 5, l31k = ll & 31;
        float v = acc[m][n][r] + bv_;
        if (mode == 0) {
          const int lane = l31k + 32 * ((d >> 3) & 1);
          Qf[((size_t)(b * 64 + kt) * 4 + (d >> 4)) * 512 + lane * 8 + (d & 7)] = f2bf(v * SCALE_LOG2E);
        } else if (mode == 1) {
          const int lane = l31k + 32 * ((d >> 3) & 1);
          Kf[((size_t)(b * 64 + kt) * 4 + (d >> 4)) * 512 + lane * 8 + (d & 7)] = f2bf(v);
        } else {
          const int j2 = 2 * (d >> 5) + ((l31k >> 4) & 1);
          const int lane = (d & 31) + 32 * ((l31k >> 3) & 1);
          Vf[((size_t)(b * 64 + kt) * 4 + j2) * 512 + lane * 8 + (l31k & 7)] = f2bf(v);
        }
      }
    }
}

// ---------- output projection ----------
__global__ __launch_bounds__(256) void gemm_out(
    const unsigned short* __restrict__ X2, const unsigned short* __restrict__ Wo,
    const float* __restrict__ bias, float* __restrict__ out) {
  f32x4 acc[4][4];
  gemm_tile_core(X2, Wo, blockIdx.y, blockIdx.x, acc);
  const int t = threadIdx.x, w = t >> 6, l = t & 63;
  const int l15 = l & 15, l4 = l >> 4;
  const int wm = w >> 1, wn = w & 1;
  const int i0 = blockIdx.y * 128 + wm * 64 + 4 * l4;
  const int j0 = blockIdx.x * 128 + wn * 64 + l15;
#pragma unroll
  for (int m = 0; m < 4; m++)
#pragma unroll
    for (int n = 0; n < 4; n++) {
      const int j = j0 + n * 16;
      const float bv_ = bias[j];
#pragma unroll
      for (int r = 0; r < 4; r++)
        out[(size_t)(i0 + m * 16 + r) * 1024 + j] = acc[m][n][r] + bv_;
    }
}

// ---------- attention: softmax + PV step for one q-tile (R11/R12-proven) ----------
static __device__ __forceinline__ void tile_step(
    const f32x16& sa, bool diag, int l31, int g,
    float& lsum, f32x16& o0, f32x16& o1, const bf16x8 (&vf)[4]) {
  float e[16];
#pragma unroll
  for (int r = 0; r < 16; r++) e[r] = sa[r];
  if (diag) {
#pragma unroll
    for (int r = 0; r < 16; r++) {
      const int kvloc = (r & 3) + 8 * (r >> 2) + 4 * g;
      e[r] = (kvloc <= l31) ? e[r] : -30000.f;   // exp2(-30000) == 0
    }
  }
#pragma unroll
  for (int r = 0; r < 16; r++) e[r] = exp2f(e[r]);
  const float s0 = (e[0] + e[1]) + (e[2] + e[3]),   s1 = (e[4] + e[5]) + (e[6] + e[7]);
  const float s2 = (e[8] + e[9]) + (e[10] + e[11]), s3 = (e[12] + e[13]) + (e[14] + e[15]);
  lsum += (s0 + s1) + (s2 + s3);

  // P -> bf16 words; redistribute to PV B-operand layout via lane^32 (R7/R9-proven)
  unsigned int u[8], pu[8];
#pragma unroll
  for (int i = 0; i < 8; i++) u[i] = cvt_pk_bf16(e[2 * i], e[2 * i + 1]);
#pragma unroll
  for (int i = 0; i < 8; i++) pu[i] = (unsigned int)__shfl_xor((int)u[i], 32, 64);
  u32x4 B0, B1;
  B0.x = g ? pu[2] : u[0];  B0.y = g ? pu[3] : u[1];
  B0.z = g ? u[2] : pu[0];  B0.w = g ? u[3] : pu[1];
  B1.x = g ? pu[6] : u[4];  B1.y = g ? pu[7] : u[5];
  B1.z = g ? u[6] : pu[4];  B1.w = g ? u[7] : pu[5];
  const bf16x8 pb0 = __builtin_bit_cast(bf16x8, B0);  // kv 0..15
  const bf16x8 pb1 = __builtin_bit_cast(bf16x8, B1);  // kv 16..31
  o0 = __builtin_amdgcn_mfma_f32_32x32x16_bf16(vf[0], pb0, o0, 0, 0, 0);
  o0 = __builtin_amdgcn_mfma_f32_32x32x16_bf16(vf[1], pb1, o0, 0, 0, 0);
  o1 = __builtin_amdgcn_mfma_f32_32x32x16_bf16(vf[2], pb0, o1, 0, 0, 0);
  o1 = __builtin_amdgcn_mfma_f32_32x32x16_bf16(vf[3], pb1, o1, 0, 0, 0);
}

// ---------- causal flash attention, opposite-paired q-tiles (R12-exact revert) ----------
// R15: R13/R14 pipelining attempts both regressed (LDS-staging spilled; asm pinning
// rigidified the schedule). The compiler's natural schedule of the C++ clamped
// prefetch is this structure's best-known config — keep it.
__global__ __launch_bounds__(256, 2) void attn_kernel(
    const unsigned short* __restrict__ Qf, const unsigned short* __restrict__ Kf,
    const unsigned short* __restrict__ Vf, unsigned short* __restrict__ X2) {
  __shared__ float po[4 * 64 * 17];
  __shared__ float lb[2][4][32];

  const unsigned id = blockIdx.x;              // 1024 blocks
  const int b = (id & 7) * 4 + ((id >> 3) & 3);
  const int p = id >> 5;                       // 0..31: t1 = p, t2 = 63-p
  const int t2 = 63 - p;

  const int w = threadIdx.x >> 6, l = threadIdx.x & 63;
  const int l31 = l & 31, g = l >> 5;

  const unsigned short* qp1 = Qf + ((size_t)(b * 64 + p) * 4) * 512 + l * 8;
  const unsigned short* qp2 = Qf + ((size_t)(b * 64 + t2) * 4) * 512 + l * 8;
  bf16x8 qf1[4], qf2[4];
#pragma unroll
  for (int s = 0; s < 4; s++) { qf1[s] = *(const bf16x8*)(qp1 + s * 512); qf2[s] = *(const bf16x8*)(qp2 + s * 512); }

  f32x16 z;
#pragma unroll
  for (int r = 0; r < 16; r++) z[r] = 0.f;
  f32x16 o10 = z, o11 = z, o20 = z, o21 = z;
  float ls1 = 0.f, ls2 = 0.f;

  const unsigned short* kb_ = Kf + (size_t)b * 131072;
  const unsigned short* vb_ = Vf + (size_t)b * 131072;

  bf16x8 kf[4], vf[4];
  {
    const unsigned short* kp = kb_ + w * 2048 + l * 8;
    const unsigned short* vp = vb_ + w * 2048 + l * 8;
#pragma unroll
    for (int s = 0; s < 4; s++) { kf[s] = *(const bf16x8*)(kp + s * 512); vf[s] = *(const bf16x8*)(vp + s * 512); }
  }

  for (int kt = w; kt <= t2; kt += 4) {
    // prefetch next tile (clamped -> branchless; duplicate last load is an L2 hit)
    const int ktn = (kt + 4 <= t2) ? kt + 4 : t2;
    const unsigned short* kp = kb_ + ktn * 2048 + l * 8;
    const unsigned short* vp = vb_ + ktn * 2048 + l * 8;
    bf16x8 kn[4], vn[4];
#pragma unroll
    for (int s = 0; s < 4; s++) { kn[s] = *(const bf16x8*)(kp + s * 512); vn[s] = *(const bf16x8*)(vp + s * 512); }
    __builtin_amdgcn_sched_barrier(0);

    // tile2 (always active)
    f32x16 sa = __builtin_amdgcn_mfma_f32_32x32x16_bf16(kf[0], qf2[0], z, 0, 0, 0);
#pragma unroll
    for (int s = 1; s < 4; s++) sa = __builtin_amdgcn_mfma_f32_32x32x16_bf16(kf[s], qf2[s], sa, 0, 0, 0);
    tile_step(sa, kt == t2, l31, g, ls2, o20, o21, vf);

    // tile1 (active while kt <= p; wave-uniform branch)
    if (kt <= p) {
      f32x16 sb = __builtin_amdgcn_mfma_f32_32x32x16_bf16(kf[0], qf1[0], z, 0, 0, 0);
#pragma unroll
      for (int s = 1; s < 4; s++) sb = __builtin_amdgcn_mfma_f32_32x32x16_bf16(kf[s], qf1[s], sb, 0, 0, 0);
      tile_step(sb, kt == p, l31, g, ls1, o10, o11, vf);
    }

#pragma unroll
    for (int s = 0; s < 4; s++) { kf[s] = kn[s]; vf[s] = vn[s]; }
  }

  // ---- cross-wave combine: 4 LDS passes (t1.o0, t1.o1, t2.o0, t2.o1); no max weights ----
  const float ls1f = ls1 + __shfl_xor(ls1, 32, 64);   // merge g=0/g=1 halves
  const float ls2f = ls2 + __shfl_xor(ls2, 32, 64);
  float* mypo = po + (w * 64 + l) * 17;
  if (l < 32) { lb[0][w][l] = ls1f; lb[1][w][l] = ls2f; }
#pragma unroll
  for (int r = 0; r < 16; r++) mypo[r] = o10[r];
  __syncthreads();

  const float inv1 = 1.f / (lb[0][0][l31] + lb[0][1][l31] + lb[0][2][l31] + lb[0][3][l31]);
  const float inv2 = 1.f / (lb[1][0][l31] + lb[1][1][l31] + lb[1][2][l31] + lb[1][3][l31]);

  const int n_ = b >> 4, h = b & 15;
  unsigned short* orow1 = X2 + ((size_t)((32 * p + l31) * 2 + n_)) * 1024 + h * 64;
  unsigned short* orow2 = X2 + ((size_t)((32 * t2 + l31) * 2 + n_)) * 1024 + h * 64;
  const int dbase = 8 * w + 4 * g;
  float c[4];

  // pass 1: t1 low half (already stored)
#pragma unroll
  for (int j = 0; j < 4; j++) c[j] = 0.f;
#pragma unroll
  for (int s = 0; s < 4; s++) {
    const float* pp = po + (s * 64 + l) * 17 + w * 4;
#pragma unroll
    for (int j = 0; j < 4; j++) c[j] += pp[j];
  }
#pragma unroll
  for (int j = 0; j < 4; j++) orow1[dbase + j] = f2bf(c[j] * inv1);
  __syncthreads();

  // pass 2: t1 high half
#pragma unroll
  for (int r = 0; r < 16; r++) mypo[r] = o11[r];
  __syncthreads();
#pragma unroll
  for (int j = 0; j < 4; j++) c[j] = 0.f;
#pragma unroll
  for (int s = 0; s < 4; s++) {
    const float* pp = po + (s * 64 + l) * 17 + w * 4;
#pragma unroll
    for (int j = 0; j < 4; j++) c[j] += pp[j];
  }
#pragma unroll
  for (int j = 0; j < 4; j++) orow1[32 + dbase + j] = f2bf(c[j] * inv1);
  __syncthreads();

  // pass 3: t2 low half
#pragma unroll
  for (int r = 0; r < 16; r++) mypo[r] = o20[r];
  __syncthreads();
#pragma unroll
  for (int j = 0; j < 4; j++) c[j] = 0.f;
#pragma unroll
  for (int s = 0; s < 4; s++) {
    const float* pp = po + (s * 64 + l) * 17 + w * 4;
#pragma unroll
    for (int j = 0; j < 4; j++) c[j] += pp[j];
  }
#pragma unroll
  for (int j = 0; j < 4; j++) orow2[dbase + j] = f2bf(c[j] * inv2);
  __syncthreads();

  // pass 4: t2 high half
#pragma unroll
  for (int r = 0; r < 16; r++) mypo[r] = o21[r];
  __syncthreads();
#pragma unroll
  for (int j = 0; j < 4; j++) c[j] = 0.f;
#pragma unroll
  for (int s = 0; s < 4; s++) {
    const float* pp = po + (s * 64 + l) * 17 + w * 4;
#pragma unroll
    for (int j = 0; j < 4; j++) c[j] += pp[j];
  }
#pragma unroll
  for (int j = 0; j < 4; j++) orow2[32 + dbase + j] = f2bf(c[j] * inv2);
}

// ---------- launch ----------
extern "C" void kernel_launch(void* const* d_in, const int* in_sizes, int n_in,
                              void* d_out, int out_size, void* d_ws, size_t ws_size,
                              hipStream_t stream) {
  const float* query    = (const float*)d_in[0];
  const float* q_proj   = (const float*)d_in[1];
  const float* q_bias   = (const float*)d_in[2];
  const float* k_proj   = (const float*)d_in[3];
  const float* k_bias   = (const float*)d_in[4];
  const float* v_proj   = (const float*)d_in[5];
  const float* v_bias   = (const float*)d_in[6];
  const float* out_proj = (const float*)d_in[7];
  const float* out_bias = (const float*)d_in[8];
  float* out = (float*)d_out;

  char* ws = (char*)d_ws;
  unsigned short* Xq = (unsigned short*)(ws);                    // [4096][1024] bf16, 8 MiB
  unsigned short* Wq = (unsigned short*)(ws + (8u << 20));       // 2 MiB each, consecutive
  unsigned short* Qf = (unsigned short*)(ws + (16u << 20));      // frag layout, 8 MiB
  unsigned short* Kf = (unsigned short*)(ws + (24u << 20));      // frag layout, 8 MiB
  unsigned short* Vf = (unsigned short*)(ws + (32u << 20));      // frag layout, 8 MiB
  unsigned short* X2 = (unsigned short*)(ws + (40u << 20));      // [4096][1024], 8 MiB
  unsigned short* Wk = Wq + 1048576;
  unsigned short* Wv = Wq + 2097152;
  unsigned short* Wo = Wq + 3145728;

  cvt_all<<<8192, 256, 0, stream>>>(query, q_proj, k_proj, v_proj, out_proj, Xq, Wq);

  gemm_qkv<<<dim3(8, 32, 3), 256, 0, stream>>>(Xq, Wq, Wk, Wv, q_bias, k_bias, v_bias, Qf, Kf, Vf);
  attn_kernel<<<1024, 256, 0, stream>>>(Qf, Kf, Vf, X2);
  gemm_out<<<dim3(8, 32), 256, 0, stream>>>(X2, Wo, out_bias, out);
}